// Round 11
// baseline (124.762 us; speedup 1.0000x reference)
//
#include <hip/hip_runtime.h>
#include <math.h>

#define B_ 2
#define H_ 8
#define L_ 2048
#define D_ 64
#define BM 32          // rows per WG: waves 0-3 -> rows 0-15, waves 4-7 -> 16-31
#define BN 128         // cols per K tile
#define NJ (L_ / BN)   // 16 tiles
#define NT 512         // threads per WG
#define L2E 1.4426950408889634f

typedef _Float16 half8 __attribute__((ext_vector_type(8)));
typedef __attribute__((ext_vector_type(4))) float f4;

#define MFMA16F(a, b, c) __builtin_amdgcn_mfma_f32_16x16x32_f16(a, b, c, 0, 0, 0)

struct LdsT {
  half8  kth[2][BN * 8];   // 32 KB double-buffered; idx = col*8 + (slot^(col&7))
  float2 ckt[BN];          // fallback-only per-tile col factors
  float  muv[2][D_];
  float  er0[BM], er1[BM]; // pi_c * exp2(rq_c) per row
  float  red[4][BM];
};

__device__ inline half8 cvt8(const float4& a0, const float4& a1) {
  half8 r;
  r[0] = (_Float16)a0.x; r[1] = (_Float16)a0.y;
  r[2] = (_Float16)a0.z; r[3] = (_Float16)a0.w;
  r[4] = (_Float16)a1.x; r[5] = (_Float16)a1.y;
  r[6] = (_Float16)a1.z; r[7] = (_Float16)a1.w;
  return r;
}

// Precompute: col factors ec_c = exp2(L2E*(s*|k-mu_c|^2 - neg)), and K as
// pre-swizzled fp16: wh[(bh*L+c)*8+g'] = fp16(k[c][8*(g'^(c&7)) .. +7]).
__global__ __launch_bounds__(256) void prep_kernel(
    const float* __restrict__ k, const float* __restrict__ mask,
    const float* __restrict__ mu, float2* __restrict__ ck,
    half8* __restrict__ wh)
{
  int bh = blockIdx.x >> 3;
  int c  = (blockIdx.x & 7) * 256 + threadIdx.x;
  int b  = bh >> 3, h = bh & 7;
  const float s = -0.0625f;  // -0.5 / sqrt(64)
  const float* kp  = k  + ((size_t)bh * L_ + c) * D_;
  const float* mu0 = mu + (size_t)h * D_;
  const float* mu1 = mu + (size_t)(H_ * D_) + (size_t)h * D_;
  float x[D_];
#pragma unroll
  for (int d = 0; d < D_; d += 4)
    *reinterpret_cast<float4*>(&x[d]) = *reinterpret_cast<const float4*>(kp + d);
  float s0 = 0.f, s1 = 0.f;
#pragma unroll
  for (int d = 0; d < D_; ++d) {
    float a = x[d] - mu0[d]; s0 += a * a;
    float bb = x[d] - mu1[d]; s1 += bb * bb;
  }
  float neg = 1.0e6f * (1.0f - mask[(size_t)b * L_ + c]);
  ck[(size_t)bh * L_ + c] = make_float2(exp2f((s * s0 - neg) * L2E),
                                        exp2f((s * s1 - neg) * L2E));
#pragma unroll
  for (int gp = 0; gp < 8; ++gp) {
    int g = gp ^ (c & 7);
    wh[((size_t)bh * L_ + c) * 8 + gp] =
        cvt8(*reinterpret_cast<const float4*>(&x[8 * g]),
             *reinterpret_cast<const float4*>(&x[8 * g + 4]));
  }
}

template <bool USE_WS>
__global__ __launch_bounds__(NT, 8) void mg_kernel(
    const float* __restrict__ q, const float* __restrict__ kk,
    const float* __restrict__ mask, const float* __restrict__ mu,
    const float* __restrict__ pi, const float2* __restrict__ ckw,
    const half8* __restrict__ wh, float* __restrict__ out)
{
  extern __shared__ __align__(16) char smem_raw[];
  LdsT& S = *reinterpret_cast<LdsT*>(smem_raw);
  const int t = threadIdx.x;
  int bid = blockIdx.x;
  int vwg = (bid & 7) * 128 + (bid >> 3);   // XCD-chunked, bijective (1024%8==0)
  int bh  = vwg >> 6;
  int rb  = vwg & 63;
  int b = bh >> 3, h = bh & 7;
  int row0 = rb * BM;

  const int w  = t >> 6;          // wave 0..7
  const int ln = t & 63;
  const int ci = ln & 15;         // col lane / A-row lane
  const int kg = ln >> 4;         // k-group lane
  const int x7 = ci & 7;
  const int wc = w & 3;           // col chunk 0..3
  const int wr = (w >> 2) * 16;   // row-block base 0 or 16

  const float s   = -0.0625f;
  const float DDC = 0.125f * L2E;   // -2s * log2e

  const float*  maskb = mask + (size_t)b * L_;
  const float2* ckb   = ckw + (size_t)bh * L_;
  const float4* kb4   = (const float4*)(kk + (size_t)bh * L_ * D_);
  const float4* whb4  = (const float4*)(wh + (size_t)bh * (L_ * 8));

  if (t < 2 * D_)
    S.muv[t >> 6][t & 63] =
        mu[(size_t)(t >> 6) * (H_ * D_) + (size_t)h * D_ + (t & 63)];

  // A-fragments: 16 rows per wave-group, fp16
  half8 ah[2];
  {
    const float* qrow = q + ((size_t)bh * L_ + row0 + wr + ci) * D_;
#pragma unroll
    for (int h2 = 0; h2 < 2; ++h2) {
      float4 a0 = *reinterpret_cast<const float4*>(qrow + 32 * h2 + kg * 8);
      float4 a1 = *reinterpret_cast<const float4*>(qrow + 32 * h2 + kg * 8 + 4);
      ah[h2] = cvt8(a0, a1);
    }
  }

  // pipeline registers (tile staged via VGPRs; loads survive barriers)
  float4 v0, v1;
  if (USE_WS) { v0 = whb4[t]; v1 = whb4[t + NT]; }   // tile 0
  __syncthreads();   // muv visible

  // per-row factors er_c = pi_c * exp2(L2E*(s*q^2 + 2s*(q.mu_c)))
  if (t < BM) {
    float pi0 = fminf(fmaxf(pi[0], 0.f), 1.f);
    float pi1 = fminf(fmaxf(pi[1], 0.f), 1.f);
    const float* qr = q + ((size_t)bh * L_ + row0 + t) * D_;
    float a0 = 0.f, a1 = 0.f, a2 = 0.f;
#pragma unroll
    for (int dq = 0; dq < 16; ++dq) {
      float4 qv = *reinterpret_cast<const float4*>(qr + 4 * dq);
      a0 += qv.x * qv.x + qv.y * qv.y + qv.z * qv.z + qv.w * qv.w;
      a1 += qv.x * S.muv[0][4*dq] + qv.y * S.muv[0][4*dq+1] +
            qv.z * S.muv[0][4*dq+2] + qv.w * S.muv[0][4*dq+3];
      a2 += qv.x * S.muv[1][4*dq] + qv.y * S.muv[1][4*dq+1] +
            qv.z * S.muv[1][4*dq+2] + qv.w * S.muv[1][4*dq+3];
    }
    S.er0[t] = pi0 * exp2f((s * a0 + 2.f * s * a1) * L2E);
    S.er1[t] = pi1 * exp2f((s * a0 + 2.f * s * a2) * L2E);
  }

  if (USE_WS) {
    // tile0 -> buf0; prefetch tile1
    S.kth[0][t]      = __builtin_bit_cast(half8, v0);
    S.kth[0][t + NT] = __builtin_bit_cast(half8, v1);
    v0 = whb4[(BN * 8) + t];
    v1 = whb4[(BN * 8) + t + NT];
  }
  __syncthreads();   // er + buf0 visible

  float e0r[4], e1r[4];
#pragma unroll
  for (int reg = 0; reg < 4; ++reg) {
    e0r[reg] = S.er0[wr + kg * 4 + reg];
    e1r[reg] = S.er1[wr + kg * 4 + reg];
  }

  // fallback staging (R10-proven two-barrier structure)
  auto STAGE_FB = [&](int j) {
#pragma unroll
    for (int i = 0; i < 2; ++i) {
      int u = t + NT * i;
      int col = u >> 3, gp = u & 7, g = gp ^ (col & 7);
      float4 x0 = kb4[(size_t)(j * BN + col) * 16 + 2 * g];
      float4 x1 = kb4[(size_t)(j * BN + col) * 16 + 2 * g + 1];
      S.kth[0][u] = cvt8(x0, x1);
    }
    if (t < BN) {
      const float* kc = kk + ((size_t)bh * L_ + j * BN + t) * D_;
      float s0 = 0.f, s1 = 0.f;
#pragma unroll
      for (int dq = 0; dq < 16; ++dq) {
        float4 kv = *reinterpret_cast<const float4*>(kc + 4 * dq);
        float a;
        a = kv.x - S.muv[0][4*dq];   s0 += a * a;
        a = kv.y - S.muv[0][4*dq+1]; s0 += a * a;
        a = kv.z - S.muv[0][4*dq+2]; s0 += a * a;
        a = kv.w - S.muv[0][4*dq+3]; s0 += a * a;
        a = kv.x - S.muv[1][4*dq];   s1 += a * a;
        a = kv.y - S.muv[1][4*dq+1]; s1 += a * a;
        a = kv.z - S.muv[1][4*dq+2]; s1 += a * a;
        a = kv.w - S.muv[1][4*dq+3]; s1 += a * a;
      }
      float neg = 1.0e6f * (1.0f - maskb[j * BN + t]);
      S.ckt[t] = make_float2(exp2f((s * s0 - neg) * L2E),
                             exp2f((s * s1 - neg) * L2E));
    }
  };

  // ---------------- PASS A: row sums only ----------------------------------
  float rsum[4] = {0.f, 0.f, 0.f, 0.f};
  int cur = 0;
#pragma unroll 1
  for (int j = 0; j < NJ; ++j) {
    float2 ec[2];
    if (USE_WS) {
      if (j + 1 < NJ) {   // write tile j+1 (regs loaded last iteration)
        S.kth[cur ^ 1][t]      = __builtin_bit_cast(half8, v0);
        S.kth[cur ^ 1][t + NT] = __builtin_bit_cast(half8, v1);
      }
      if (j + 2 < NJ) {   // issue tile j+2
        v0 = whb4[(size_t)(j + 2) * (BN * 8) + t];
        v1 = whb4[(size_t)(j + 2) * (BN * 8) + t + NT];
      }
#pragma unroll
      for (int n = 0; n < 2; ++n)
        ec[n] = ckb[j * BN + wc * 32 + 16 * n + ci];
    } else {
      __syncthreads();
      STAGE_FB(j);
      __syncthreads();
#pragma unroll
      for (int n = 0; n < 2; ++n) ec[n] = S.ckt[wc * 32 + 16 * n + ci];
    }
    const int rbuf = USE_WS ? cur : 0;
#pragma unroll
    for (int n = 0; n < 2; ++n) {
      int base = (wc * 32 + n * 16 + ci) * 8;
      half8 b0 = S.kth[rbuf][base + (kg ^ x7)];
      half8 b1 = S.kth[rbuf][base + ((4 + kg) ^ x7)];
      f4 acc = {0.f, 0.f, 0.f, 0.f};
      acc = MFMA16F(ah[0], b0, acc);
      acc = MFMA16F(ah[1], b1, acc);
#pragma unroll
      for (int reg = 0; reg < 4; ++reg) {
        float g2 = __builtin_amdgcn_exp2f(DDC * acc[reg]);
        float m  = fmaf(e0r[reg], ec[n].x, e1r[reg] * ec[n].y);
        rsum[reg] = fmaf(g2, m, rsum[reg]);
      }
    }
    if (USE_WS) { __syncthreads(); cur ^= 1; }
  }
  // after pass A (WS): cur==0, buf1 = tile15, buf0 = tile14.

  if (USE_WS && NJ >= 3) {   // issue tile 13 under the reduce
    v0 = whb4[(size_t)(NJ - 3) * (BN * 8) + t];
    v1 = whb4[(size_t)(NJ - 3) * (BN * 8) + t + NT];
  }

  // row-sum reduce: 16 col-lanes, then 4 col-waves; fold inv into row factors
#pragma unroll
  for (int reg = 0; reg < 4; ++reg) {
    float v = rsum[reg];
    v += __shfl_xor(v, 1, 64);
    v += __shfl_xor(v, 2, 64);
    v += __shfl_xor(v, 4, 64);
    v += __shfl_xor(v, 8, 64);
    if (ci == 0) S.red[wc][wr + kg * 4 + reg] = v;
  }
  __syncthreads();
#pragma unroll
  for (int reg = 0; reg < 4; ++reg) {
    int r = wr + kg * 4 + reg;
    float inv = 1.0f / (S.red[0][r] + S.red[1][r] + S.red[2][r] + S.red[3][r]);
    e0r[reg] *= inv;
    e1r[reg] *= inv;
  }

  // ---------------- PASS B: recompute + direct normalized store ------------
  // Descending j; tiles 15 (buf1) and 14 (buf0) still resident from pass A.
  float* ob = out + ((size_t)bh * L_ + row0 + wr + kg * 4) * L_ + wc * 32 + ci;
  cur = 1;
#pragma unroll 1
  for (int jj = 0; jj < NJ; ++jj) {
    const int j = NJ - 1 - jj;
    float2 ec[2];
    if (USE_WS) {
      if (jj >= 1 && j >= 1) {   // write tile j-1 (regs from previous iter)
        S.kth[cur ^ 1][t]      = __builtin_bit_cast(half8, v0);
        S.kth[cur ^ 1][t + NT] = __builtin_bit_cast(half8, v1);
      }
      if (j >= 2) {              // issue tile j-2
        v0 = whb4[(size_t)(j - 2) * (BN * 8) + t];
        v1 = whb4[(size_t)(j - 2) * (BN * 8) + t + NT];
      }
#pragma unroll
      for (int n = 0; n < 2; ++n)
        ec[n] = ckb[j * BN + wc * 32 + 16 * n + ci];
    } else {
      if (jj != 0) {
        __syncthreads();
        STAGE_FB(j);
        __syncthreads();
      }
#pragma unroll
      for (int n = 0; n < 2; ++n) ec[n] = S.ckt[wc * 32 + 16 * n + ci];
    }
    const int rbuf = USE_WS ? cur : 0;
#pragma unroll
    for (int n = 0; n < 2; ++n) {
      int base = (wc * 32 + n * 16 + ci) * 8;
      half8 b0 = S.kth[rbuf][base + (kg ^ x7)];
      half8 b1 = S.kth[rbuf][base + ((4 + kg) ^ x7)];
      f4 acc = {0.f, 0.f, 0.f, 0.f};
      acc = MFMA16F(ah[0], b0, acc);
      acc = MFMA16F(ah[1], b1, acc);
#pragma unroll
      for (int reg = 0; reg < 4; ++reg) {
        float g2 = __builtin_amdgcn_exp2f(DDC * acc[reg]);
        float m  = fmaf(e0r[reg], ec[n].x, e1r[reg] * ec[n].y);
        float p  = g2 * m;
        __builtin_nontemporal_store(
            p, ob + (size_t)reg * L_ + (j * BN + n * 16));
      }
    }
    if (USE_WS) { __syncthreads(); cur ^= 1; }
  }
}

extern "C" void kernel_launch(void* const* d_in, const int* in_sizes, int n_in,
                              void* d_out, int out_size, void* d_ws, size_t ws_size,
                              hipStream_t stream) {
  const float* q    = (const float*)d_in[0];
  const float* k    = (const float*)d_in[1];
  const float* mask = (const float*)d_in[2];
  const float* mu   = (const float*)d_in[3];
  const float* pi   = (const float*)d_in[4];
  float* out = (float*)d_out;

  const size_t smem     = sizeof(LdsT);
  const size_t ck_bytes = (size_t)B_ * H_ * L_ * sizeof(float2);       // 256 KB
  const size_t wp_bytes = (size_t)B_ * H_ * L_ * D_ * sizeof(short);   // 4 MB (fp16)
  const bool use_ws = (ws_size >= ck_bytes + wp_bytes) && (d_ws != nullptr);

  if (use_ws) {
    float2* ck = (float2*)d_ws;
    half8*  wh = (half8*)((char*)d_ws + ck_bytes);
    (void)hipFuncSetAttribute(reinterpret_cast<const void*>(&mg_kernel<true>),
                              hipFuncAttributeMaxDynamicSharedMemorySize, (int)smem);
    prep_kernel<<<dim3(B_ * H_ * 8), dim3(256), 0, stream>>>(k, mask, mu, ck, wh);
    mg_kernel<true><<<dim3(B_ * H_ * (L_ / BM)), dim3(NT), smem, stream>>>(
        q, k, mask, mu, pi, ck, wh, out);
  } else {
    (void)hipFuncSetAttribute(reinterpret_cast<const void*>(&mg_kernel<false>),
                              hipFuncAttributeMaxDynamicSharedMemorySize, (int)smem);
    mg_kernel<false><<<dim3(B_ * H_ * (L_ / BM)), dim3(NT), smem, stream>>>(
        q, k, mask, mu, pi, nullptr, nullptr, out);
  }
}